// Round 11
// baseline (142.149 us; speedup 1.0000x reference)
//
#include <hip/hip_runtime.h>
#include <hip/hip_bf16.h>

typedef _Float16 half8 __attribute__((ext_vector_type(8)));
typedef _Float16 half4v __attribute__((ext_vector_type(4)));
typedef float floatx4 __attribute__((ext_vector_type(4)));

// Problem constants: B=8, N=1024, D=512, H=8, DH=64
#define BB 8
#define NN 1024
#define DD 512
#define HH 8
#define DHH 64
#define LOG2E 1.4426950408889634f

// hardware 2^x (v_exp_f32)
#define EXP2F(x) __builtin_amdgcn_exp2f(x)

// async global->LDS, 16B per lane, dest = wave-uniform base + lane*16
__device__ __forceinline__ void gload_lds16(const _Float16* g, _Float16* l) {
    __builtin_amdgcn_global_load_lds(
        (const __attribute__((address_space(1))) void*)g,
        (__attribute__((address_space(3))) void*)l, 16, 0, 0);
}

// ---------------- W fp32->fp16 transpose only (unchanged from round 8) ----------------
// 192 blocks: 3 matrices x 64 tiles of 64x64. Wq pre-scaled by log2(e).
__global__ __launch_bounds__(256) void cvt_kernel(const float* __restrict__ Wq,
                                                  const float* __restrict__ Wk,
                                                  const float* __restrict__ Wv,
                                                  _Float16* __restrict__ Wt) {
    __shared__ __align__(16) _Float16 tb[64][72];
    int t = blockIdx.x;                // 0..191
    int tid = threadIdx.x;
    int which = t >> 6;                // /64
    int rem = t & 63;
    int kt = (rem >> 3) * 64, nt = (rem & 7) * 64;
    const float* W = (which == 0) ? Wq : (which == 1) ? Wk : Wv;
    float wscale = (which == 0) ? LOG2E : 1.0f;
    _Float16* Wto = Wt + (size_t)which * DD * DD;
    for (int i = 0; i < 16; i++) {
        int idx = tid + i * 256;
        int r = idx >> 6, c = idx & 63;
        tb[c][r] = (_Float16)(W[(size_t)(kt + r) * DD + nt + c] * wscale);
    }
    __syncthreads();
    for (int i = 0; i < 16; i++) {
        int idx = tid + i * 256;
        int r = idx >> 6, c = idx & 63;
        Wto[(size_t)(nt + r) * DD + kt + c] = tb[r][c];
    }
}

// ---------------- QKV projection, 128x128 tile, BK=64, XOR-SWIZZLED LDS ----------------
// Round 11: the Ws/Xs fragment reads were an ~8-way bank conflict (16 lanes,
// 16 different rows, same column; row stride 64B -> 2 distinct banks). Fix per
// T2: chunk ^= row&7. W staged via PRE-SWIZZLED GLOBAL SOURCE (linear gload_lds
// dest); x staged via swizzled ds_write addr; reads use the same XOR -> 2-way
// (free). BK=64 halves barrier count (8 iters, 32 MFMA per barrier pair).
// LDS 32KB. Token-major grid (64,4,3) for XCD L2 x-reuse (round 8).
__global__ __launch_bounds__(256) void qkv_gemm_kernel(const float* __restrict__ x,
                                                       const _Float16* __restrict__ Wt,
                                                       const float* __restrict__ bq,
                                                       const float* __restrict__ bk,
                                                       const float* __restrict__ bv,
                                                       _Float16* __restrict__ QKV) {
    __shared__ __align__(16) _Float16 Ws[128 * 64];   // W rows (features), swizzled
    __shared__ __align__(16) _Float16 Xs[128 * 64];   // x rows (tokens),  swizzled

    int which = blockIdx.z;
    const _Float16* Wtw = Wt + (size_t)which * DD * DD;
    const float* bias = (which == 0) ? bq : (which == 1) ? bk : bv;
    const float bscale = (which == 0) ? LOG2E : 1.0f;

    int tid = threadIdx.x;
    int wave = tid >> 6, lane = tid & 63;
    int quad = lane >> 4, l16 = lane & 15;
    int l16sw = l16 & 7;
    int wm = wave >> 1, wn = wave & 1;
    int mBase = blockIdx.x * 128;   // tokens  (token-major for XCD L2 reuse)
    int nBase = blockIdx.y * 128;   // features

    // W staging: rows of 64 halves (128B = 8 chunks). gload j covers rows
    // wave*32 + j*8 + (lane>>3), chunk lane&7 (linear dest). Swizzle via source:
    // fetch global chunk (lane&7)^(row&7), row&7 = lane>>3.
    int wrow7 = lane >> 3;                         // row&7 within each 8-row gload
    int wchunk = (lane & 7) ^ wrow7;               // pre-swizzled source chunk
    const _Float16* wg = Wtw + (size_t)(nBase + wave * 32 + wrow7) * DD + wchunk * 8;
    _Float16* wl = Ws + (wave * 32) * 64;

    // x staging: fp32 global -> regs -> f16 -> swizzled ds_write.
    // rows srow, srow+16; chunks (khalf*4 + (lane&3)) ^ (srow&7).
    int sxrow = wave * 32 + (lane >> 2);           // 16 rows per pass
    int sxr7 = (lane >> 2) & 7;                    // (srow&7), same for srow+16
    const float* xg = x + (size_t)(mBase + sxrow) * DD + (lane & 3) * 8;

    floatx4 acc[4][4];
    for (int i = 0; i < 4; i++)
        for (int j = 0; j < 4; j++) acc[i][j] = (floatx4){0.f, 0.f, 0.f, 0.f};

    for (int kk = 0; kk < DD; kk += 64) {
        __syncthreads();
        // W: 4 async gloads cover 32 rows x 64 halves for this wave
        for (int j = 0; j < 4; j++)
            gload_lds16(wg + (size_t)(j * 8) * DD + kk, wl + (j * 8) * 64);
        // x: 2 row-groups x 2 k-halves, converted in-register
        for (int rg = 0; rg < 2; rg++) {
            int row = sxrow + rg * 16;
            const float* xr = xg + (size_t)(rg * 16) * DD + kk;
            for (int kh = 0; kh < 2; kh++) {
                float4 a0 = *(const float4*)(xr + kh * 32);
                float4 a1 = *(const float4*)(xr + kh * 32 + 4);
                half8 ha;
                ha[0] = (_Float16)a0.x; ha[1] = (_Float16)a0.y;
                ha[2] = (_Float16)a0.z; ha[3] = (_Float16)a0.w;
                ha[4] = (_Float16)a1.x; ha[5] = (_Float16)a1.y;
                ha[6] = (_Float16)a1.z; ha[7] = (_Float16)a1.w;
                int chunk = (kh * 4 + (lane & 3)) ^ sxr7;
                *(half8*)&Xs[row * 64 + chunk * 8] = ha;
            }
        }
        __syncthreads();

        // fragments read with the same XOR; per-ks to cap VGPR liveness
        for (int ks = 0; ks < 2; ks++) {
            half8 af[4], bf[4];
            if (which < 2) {
                for (int i = 0; i < 4; i++)
                    af[i] = *(const half8*)&Ws[(wm * 64 + i * 16 + l16) * 64
                                               + (((ks * 4 + quad) ^ l16sw) * 8)];
                for (int j = 0; j < 4; j++)
                    bf[j] = *(const half8*)&Xs[(wn * 64 + j * 16 + l16) * 64
                                               + (((ks * 4 + quad) ^ l16sw) * 8)];
            } else {
                for (int i = 0; i < 4; i++)
                    af[i] = *(const half8*)&Xs[(wm * 64 + i * 16 + l16) * 64
                                               + (((ks * 4 + quad) ^ l16sw) * 8)];
                for (int j = 0; j < 4; j++)
                    bf[j] = *(const half8*)&Ws[(wn * 64 + j * 16 + l16) * 64
                                               + (((ks * 4 + quad) ^ l16sw) * 8)];
            }
            for (int i = 0; i < 4; i++)
                for (int j = 0; j < 4; j++)
                    acc[i][j] = __builtin_amdgcn_mfma_f32_16x16x32_f16(af[i], bf[j], acc[i][j], 0, 0, 0);
        }
    }

    if (which < 2) {
        // C rows = features (A=W), cols = tokens (B=x)
        _Float16* out = QKV + (size_t)which * (BB * NN) * DD;
        for (int i = 0; i < 4; i++) {
            int feat0 = nBase + wm * 64 + i * 16 + quad * 4;
            float4 b4 = *(const float4*)&bias[feat0];
            b4.x *= bscale; b4.y *= bscale; b4.z *= bscale; b4.w *= bscale;
            for (int j = 0; j < 4; j++) {
                int token = mBase + wn * 64 + j * 16 + l16;
                half4v pack;
                pack[0] = (_Float16)(acc[i][j][0] + b4.x);
                pack[1] = (_Float16)(acc[i][j][1] + b4.y);
                pack[2] = (_Float16)(acc[i][j][2] + b4.z);
                pack[3] = (_Float16)(acc[i][j][3] + b4.w);
                *(half4v*)&out[(size_t)token * DD + feat0] = pack;
            }
        }
    } else {
        // C rows = tokens (A=x), cols = features. VT[(b*512+feat)*1024 + n]
        _Float16* VT = QKV + (size_t)2 * (BB * NN) * DD;
        for (int j = 0; j < 4; j++) {
            int col = nBase + wn * 64 + j * 16 + l16;
            float bval = bias[col];
            for (int i = 0; i < 4; i++) {
                int row0 = mBase + wm * 64 + i * 16 + quad * 4;
                int b = row0 >> 10;
                int n = row0 & 1023;
                half4v pack;
                for (int reg = 0; reg < 4; reg++) pack[reg] = (_Float16)(acc[i][j][reg] + bval);
                *(half4v*)&VT[((size_t)b * 512 + col) * 1024 + n] = pack;
            }
        }
    }
}

// per-wave K/V tile staging: 4x gload_lds16, pre-swizzled global src, linear LDS dest
__device__ __forceinline__ void stage_kv(const _Float16* kg, const _Float16* vg,
                                         _Float16* kl, _Float16* vl, int kt) {
    const _Float16* kgk = kg + (size_t)(kt * 64) * DD;
    const _Float16* vgk = vg + kt * 64;
    gload_lds16(kgk,            kl);
    gload_lds16(kgk + 8 * DD,   kl + 8 * 64);
    gload_lds16(vgk,            vl);
    gload_lds16(vgk + 8 * 1024, vl + 8 * 64);
}

// ---------------- flash attention (REVERTED to round-8 version — best total 137.4) ----------------
// EXP-FIRST softmax in exp2 domain, dbuf K/V, one barrier per tile, XCD-pinned
// mapping, s_setprio. LDS 40KB -> 4 blocks/CU. block 256 (4 waves). Br=64, Bc=64.
__global__ __launch_bounds__(256) void attn_kernel(const _Float16* __restrict__ QKV,
                                                   float* __restrict__ out) {
    const _Float16* Q  = QKV;
    const _Float16* K  = QKV + (size_t)(BB * NN) * DD;
    const _Float16* VT = QKV + (size_t)2 * (BB * NN) * DD;

    __shared__ __align__(16) _Float16 Kt[2][64 * 64];   // [key][d], swizzled
    __shared__ __align__(16) _Float16 Vt[2][64 * 64];   // [d][key], swizzled
    __shared__ __align__(16) _Float16 PT[4][16 * 64];   // per-wave [q][64 keys], swizzled

    int tid = threadIdx.x;
    int wave = tid >> 6, lane = tid & 63;
    int quad = lane >> 4, l16 = lane & 15;
    int l16sw = l16 & 7;
    // XCD-pinned decode: bid&7 tracks the XCD round-robin -> pin batch b per XCD.
    int bid = blockIdx.x;
    int b = bid & 7;
    int local = bid >> 3;      // 0..127 within XCD
    int h = local & 7;
    int qt = local >> 3;       // 0..15

    const _Float16* Qb  = Q + ((size_t)b * NN) * DD + h * DHH;
    const _Float16* Kb  = K + ((size_t)b * NN) * DD + h * DHH;
    const _Float16* VTb = VT + ((size_t)b * 512 + h * 64) * 1024;

    int qrow = qt * 64 + wave * 16 + l16;
    half8 qf0 = *(const half8*)(Qb + (size_t)qrow * DD + 0 * 32 + quad * 8);
    half8 qf1 = *(const half8*)(Qb + (size_t)qrow * DD + 1 * 32 + quad * 8);

    floatx4 o[4];
    for (int nt = 0; nt < 4; nt++) o[nt] = (floatx4){0.f, 0.f, 0.f, 0.f};
    float m_i = 0.0f, l_i = 0.f;   // m_i=0 init (exp-first)

    int srow = lane >> 3;                 // 0..7
    int schunk = (lane & 7) ^ srow;       // swizzled 16B chunk
    const _Float16* kg = Kb + (size_t)(wave * 16 + srow) * DD + schunk * 8;
    const _Float16* vg = VTb + (size_t)(wave * 16 + srow) * 1024 + schunk * 8;
    _Float16* kl0 = &Kt[0][(wave * 16) * 64];
    _Float16* vl0 = &Vt[0][(wave * 16) * 64];
    _Float16* kl1 = &Kt[1][(wave * 16) * 64];
    _Float16* vl1 = &Vt[1][(wave * 16) * 64];

    stage_kv(kg, vg, kl0, vl0, 0);

    for (int kt = 0; kt < 16; kt++) {
        int cur = kt & 1;
        __syncthreads();
        if (kt + 1 < 16)
            stage_kv(kg, vg, cur ? kl0 : kl1, cur ? vl0 : vl1, kt + 1);

        // ---- QK^T (log2 domain) ----
        floatx4 s[4];
        for (int nt = 0; nt < 4; nt++) s[nt] = (floatx4){0.f, 0.f, 0.f, 0.f};
        __builtin_amdgcn_s_setprio(1);
        for (int ks = 0; ks < 2; ks++) {
            half8 qf = ks ? qf1 : qf0;
            for (int nt = 0; nt < 4; nt++) {
                half8 kf = *(const half8*)&Kt[cur][(nt * 16 + l16) * 64
                                                   + (((ks * 4 + quad) ^ l16sw) * 8)];
                s[nt] = __builtin_amdgcn_mfma_f32_16x16x32_f16(kf, qf, s[nt], 0, 0, 0);
            }
        }
        __builtin_amdgcn_s_setprio(0);

        // ---- exp-first softmax: P with STALE m_i; max tree off critical path ----
        float a0 = fmaxf(fmaxf(s[0][0], s[0][1]), fmaxf(s[0][2], s[0][3]));
        float a1 = fmaxf(fmaxf(s[1][0], s[1][1]), fmaxf(s[1][2], s[1][3]));
        float a2 = fmaxf(fmaxf(s[2][0], s[2][1]), fmaxf(s[2][2], s[2][3]));
        float a3 = fmaxf(fmaxf(s[3][0], s[3][1]), fmaxf(s[3][2], s[3][3]));
        float mx = fmaxf(fmaxf(a0, a1), fmaxf(a2, a3));

        for (int nt = 0; nt < 4; nt++)
            for (int r = 0; r < 4; r++)
                s[nt][r] = EXP2F(s[nt][r] - m_i);
        float r0 = (s[0][0] + s[0][1]) + (s[0][2] + s[0][3]);
        float r1 = (s[1][0] + s[1][1]) + (s[1][2] + s[1][3]);
        float r2 = (s[2][0] + s[2][1]) + (s[2][2] + s[2][3]);
        float r3 = (s[3][0] + s[3][1]) + (s[3][2] + s[3][3]);
        float rs = (r0 + r1) + (r2 + r3);

        float mxs = __shfl_xor(mx, 16, 64);
        float rss = __shfl_xor(rs, 16, 64);
        mx = fmaxf(mx, mxs);
        rs += rss;
        mxs = __shfl_xor(mx, 32, 64);
        rss = __shfl_xor(rs, 32, 64);
        mx = fmaxf(mx, mxs);
        rs += rss;

        if (__any(mx > m_i + 11.5443f)) {
            float mnew = fmaxf(m_i, mx);
            float al = EXP2F(m_i - mnew);
            m_i = mnew;
            l_i *= al;
            rs *= al;
            for (int nt = 0; nt < 4; nt++)
                for (int r = 0; r < 4; r++) {
                    s[nt][r] *= al;
                    o[nt][r] *= al;
                }
        }
        l_i += rs;

        // ---- pack P^T tile to per-wave LDS (swizzled) ----
        for (int ntl = 0; ntl < 4; ntl++) {
            half4v p4;
            for (int r = 0; r < 4; r++) p4[r] = (_Float16)s[ntl][r];
            *(half4v*)&PT[wave][l16 * 64 + (((ntl * 2 + (quad >> 1)) ^ l16sw) * 8)
                               + (quad & 1) * 4] = p4;
        }

        // ---- PV ----
        __builtin_amdgcn_s_setprio(1);
        for (int ks2 = 0; ks2 < 2; ks2++) {
            half8 pf = *(const half8*)&PT[wave][l16 * 64 + (((ks2 * 4 + quad) ^ l16sw) * 8)];
            for (int nt = 0; nt < 4; nt++) {
                half8 vf = *(const half8*)&Vt[cur][(nt * 16 + l16) * 64
                                                   + (((ks2 * 4 + quad) ^ l16sw) * 8)];
                o[nt] = __builtin_amdgcn_mfma_f32_16x16x32_f16(vf, pf, o[nt], 0, 0, 0);
            }
        }
        __builtin_amdgcn_s_setprio(0);
    }

    float inv = 1.0f / l_i;
    float* outb = out + ((size_t)b * NN) * DD + h * DHH;
    int row = qt * 64 + wave * 16 + l16;
    for (int nt = 0; nt < 4; nt++) {
        float4 st;
        st.x = o[nt][0] * inv; st.y = o[nt][1] * inv;
        st.z = o[nt][2] * inv; st.w = o[nt][3] * inv;
        *(float4*)&outb[(size_t)row * DD + nt * 16 + quad * 4] = st;
    }
}

extern "C" void kernel_launch(void* const* d_in, const int* in_sizes, int n_in,
                              void* d_out, int out_size, void* d_ws, size_t ws_size,
                              hipStream_t stream) {
    const float* x  = (const float*)d_in[0];
    const float* Wq = (const float*)d_in[1];
    const float* bq = (const float*)d_in[2];
    const float* Wk = (const float*)d_in[3];
    const float* bk = (const float*)d_in[4];
    const float* Wv = (const float*)d_in[5];
    const float* bv = (const float*)d_in[6];
    float* out = (float*)d_out;

    _Float16* Wt  = (_Float16*)d_ws;
    _Float16* QKV = Wt + (size_t)3 * DD * DD;

    hipLaunchKernelGGL(cvt_kernel, dim3(192), dim3(256), 0, stream,
                       Wq, Wk, Wv, Wt);
    hipLaunchKernelGGL(qkv_gemm_kernel, dim3(64, 4, 3), dim3(256), 0, stream,
                       x, Wt, bq, bk, bv, QKV);
    hipLaunchKernelGGL(attn_kernel, dim3(1024), dim3(256), 0, stream, QKV, out);
}

// Round 12
// 134.818 us; speedup vs baseline: 1.0544x; 1.0544x over previous
//
#include <hip/hip_runtime.h>
#include <hip/hip_bf16.h>

typedef _Float16 half8 __attribute__((ext_vector_type(8)));
typedef _Float16 half4v __attribute__((ext_vector_type(4)));
typedef float floatx4 __attribute__((ext_vector_type(4)));

// Problem constants: B=8, N=1024, D=512, H=8, DH=64
#define BB 8
#define NN 1024
#define DD 512
#define HH 8
#define DHH 64
#define LOG2E 1.4426950408889634f

// hardware 2^x (v_exp_f32)
#define EXP2F(x) __builtin_amdgcn_exp2f(x)

// async global->LDS, 16B per lane, dest = wave-uniform base + lane*16
__device__ __forceinline__ void gload_lds16(const _Float16* g, _Float16* l) {
    __builtin_amdgcn_global_load_lds(
        (const __attribute__((address_space(1))) void*)g,
        (__attribute__((address_space(3))) void*)l, 16, 0, 0);
}

// ---------------- W fp32->fp16 transpose only (round-8 version) ----------------
// 192 blocks: 3 matrices x 64 tiles of 64x64. Wq pre-scaled by log2(e).
__global__ __launch_bounds__(256) void cvt_kernel(const float* __restrict__ Wq,
                                                  const float* __restrict__ Wk,
                                                  const float* __restrict__ Wv,
                                                  _Float16* __restrict__ Wt) {
    __shared__ __align__(16) _Float16 tb[64][72];
    int t = blockIdx.x;                // 0..191
    int tid = threadIdx.x;
    int which = t >> 6;                // /64
    int rem = t & 63;
    int kt = (rem >> 3) * 64, nt = (rem & 7) * 64;
    const float* W = (which == 0) ? Wq : (which == 1) ? Wk : Wv;
    float wscale = (which == 0) ? LOG2E : 1.0f;
    _Float16* Wto = Wt + (size_t)which * DD * DD;
    for (int i = 0; i < 16; i++) {
        int idx = tid + i * 256;
        int r = idx >> 6, c = idx & 63;
        tb[c][r] = (_Float16)(W[(size_t)(kt + r) * DD + nt + c] * wscale);
    }
    __syncthreads();
    for (int i = 0; i < 16; i++) {
        int idx = tid + i * 256;
        int r = idx >> 6, c = idx & 63;
        Wto[(size_t)(nt + r) * DD + kt + c] = tb[r][c];
    }
}

// ---------------- QKV projection, 128x128 tile (round-8 version, BK=32) ----------------
// x staged DIRECTLY from fp32 global (in-register f32->f16 convert + ds_write),
// W via gload_lds16. TOKEN-MAJOR grid (64,4,3): all 12 blocks sharing a token
// panel have the same bid%8 -> same XCD -> x L2-resident, fetched ~1x.
__global__ __launch_bounds__(256) void qkv_gemm_kernel(const float* __restrict__ x,
                                                       const _Float16* __restrict__ Wt,
                                                       const float* __restrict__ bq,
                                                       const float* __restrict__ bk,
                                                       const float* __restrict__ bv,
                                                       _Float16* __restrict__ QKV) {
    __shared__ __align__(16) _Float16 Ws[128 * 32];   // W rows (features)
    __shared__ __align__(16) _Float16 Xs[128 * 32];   // x rows (tokens)

    int which = blockIdx.z;
    const _Float16* Wtw = Wt + (size_t)which * DD * DD;
    const float* bias = (which == 0) ? bq : (which == 1) ? bk : bv;
    const float bscale = (which == 0) ? LOG2E : 1.0f;

    int tid = threadIdx.x;
    int wave = tid >> 6, lane = tid & 63;
    int quad = lane >> 4, l16 = lane & 15;
    int wm = wave >> 1, wn = wave & 1;
    int mBase = blockIdx.x * 128;   // tokens  (token-major for XCD L2 reuse)
    int nBase = blockIdx.y * 128;   // features

    int srow = wave * 32 + (lane >> 2);
    int scol = (lane & 3) * 8;
    const _Float16* wg = Wtw + (size_t)(nBase + srow) * DD + scol;
    const float*    xg = x   + (size_t)(mBase + srow) * DD + scol;
    _Float16* wl = Ws + (wave * 32) * 32;

    floatx4 acc[4][4];
    for (int i = 0; i < 4; i++)
        for (int j = 0; j < 4; j++) acc[i][j] = (floatx4){0.f, 0.f, 0.f, 0.f};

    for (int kk = 0; kk < DD; kk += 32) {
        __syncthreads();
        gload_lds16(wg + kk,           wl);
        gload_lds16(wg + 16 * DD + kk, wl + 16 * 32);
        float4 a0 = *(const float4*)(xg + kk);
        float4 a1 = *(const float4*)(xg + kk + 4);
        float4 b0 = *(const float4*)(xg + 16 * DD + kk);
        float4 b1 = *(const float4*)(xg + 16 * DD + kk + 4);
        half8 ha, hb;
        ha[0] = (_Float16)a0.x; ha[1] = (_Float16)a0.y; ha[2] = (_Float16)a0.z; ha[3] = (_Float16)a0.w;
        ha[4] = (_Float16)a1.x; ha[5] = (_Float16)a1.y; ha[6] = (_Float16)a1.z; ha[7] = (_Float16)a1.w;
        hb[0] = (_Float16)b0.x; hb[1] = (_Float16)b0.y; hb[2] = (_Float16)b0.z; hb[3] = (_Float16)b0.w;
        hb[4] = (_Float16)b1.x; hb[5] = (_Float16)b1.y; hb[6] = (_Float16)b1.z; hb[7] = (_Float16)b1.w;
        *(half8*)&Xs[srow * 32 + scol] = ha;
        *(half8*)&Xs[(srow + 16) * 32 + scol] = hb;
        __syncthreads();

        half8 af[4], bf[4];
        if (which < 2) {
            for (int i = 0; i < 4; i++)
                af[i] = *(const half8*)&Ws[(wm * 64 + i * 16 + l16) * 32 + quad * 8];
            for (int j = 0; j < 4; j++)
                bf[j] = *(const half8*)&Xs[(wn * 64 + j * 16 + l16) * 32 + quad * 8];
        } else {
            for (int i = 0; i < 4; i++)
                af[i] = *(const half8*)&Xs[(wm * 64 + i * 16 + l16) * 32 + quad * 8];
            for (int j = 0; j < 4; j++)
                bf[j] = *(const half8*)&Ws[(wn * 64 + j * 16 + l16) * 32 + quad * 8];
        }
        for (int i = 0; i < 4; i++)
            for (int j = 0; j < 4; j++)
                acc[i][j] = __builtin_amdgcn_mfma_f32_16x16x32_f16(af[i], bf[j], acc[i][j], 0, 0, 0);
    }

    if (which < 2) {
        _Float16* out = QKV + (size_t)which * (BB * NN) * DD;
        for (int i = 0; i < 4; i++) {
            int feat0 = nBase + wm * 64 + i * 16 + quad * 4;
            float4 b4 = *(const float4*)&bias[feat0];
            b4.x *= bscale; b4.y *= bscale; b4.z *= bscale; b4.w *= bscale;
            for (int j = 0; j < 4; j++) {
                int token = mBase + wn * 64 + j * 16 + l16;
                half4v pack;
                pack[0] = (_Float16)(acc[i][j][0] + b4.x);
                pack[1] = (_Float16)(acc[i][j][1] + b4.y);
                pack[2] = (_Float16)(acc[i][j][2] + b4.z);
                pack[3] = (_Float16)(acc[i][j][3] + b4.w);
                *(half4v*)&out[(size_t)token * DD + feat0] = pack;
            }
        }
    } else {
        _Float16* VT = QKV + (size_t)2 * (BB * NN) * DD;
        for (int j = 0; j < 4; j++) {
            int col = nBase + wn * 64 + j * 16 + l16;
            float bval = bias[col];
            for (int i = 0; i < 4; i++) {
                int row0 = mBase + wm * 64 + i * 16 + quad * 4;
                int b = row0 >> 10;
                int n = row0 & 1023;
                half4v pack;
                for (int reg = 0; reg < 4; reg++) pack[reg] = (_Float16)(acc[i][j][reg] + bval);
                *(half4v*)&VT[((size_t)b * 512 + col) * 1024 + n] = pack;
            }
        }
    }
}

// per-wave K/V tile staging: 4x gload_lds16, pre-swizzled global src, linear LDS dest
__device__ __forceinline__ void stage_kv(const _Float16* kg, const _Float16* vg,
                                         _Float16* kl, _Float16* vl, int kt) {
    const _Float16* kgk = kg + (size_t)(kt * 64) * DD;
    const _Float16* vgk = vg + kt * 64;
    gload_lds16(kgk,            kl);
    gload_lds16(kgk + 8 * DD,   kl + 8 * 64);
    gload_lds16(vgk,            vl);
    gload_lds16(vgk + 8 * 1024, vl + 8 * 64);
}

// ---------------- flash attention (round-8 version — best total 137.4) ----------------
// EXP-FIRST softmax in exp2 domain, dbuf K/V, one barrier per tile, XCD-pinned
// mapping, s_setprio. LDS 40KB -> 4 blocks/CU. block 256 (4 waves). Br=64, Bc=64.
__global__ __launch_bounds__(256) void attn_kernel(const _Float16* __restrict__ QKV,
                                                   float* __restrict__ out) {
    const _Float16* Q  = QKV;
    const _Float16* K  = QKV + (size_t)(BB * NN) * DD;
    const _Float16* VT = QKV + (size_t)2 * (BB * NN) * DD;

    __shared__ __align__(16) _Float16 Kt[2][64 * 64];   // [key][d], swizzled
    __shared__ __align__(16) _Float16 Vt[2][64 * 64];   // [d][key], swizzled
    __shared__ __align__(16) _Float16 PT[4][16 * 64];   // per-wave [q][64 keys], swizzled

    int tid = threadIdx.x;
    int wave = tid >> 6, lane = tid & 63;
    int quad = lane >> 4, l16 = lane & 15;
    int l16sw = l16 & 7;
    // XCD-pinned decode: bid&7 tracks the XCD round-robin -> pin batch b per XCD.
    int bid = blockIdx.x;
    int b = bid & 7;
    int local = bid >> 3;      // 0..127 within XCD
    int h = local & 7;
    int qt = local >> 3;       // 0..15

    const _Float16* Qb  = Q + ((size_t)b * NN) * DD + h * DHH;
    const _Float16* Kb  = K + ((size_t)b * NN) * DD + h * DHH;
    const _Float16* VTb = VT + ((size_t)b * 512 + h * 64) * 1024;

    int qrow = qt * 64 + wave * 16 + l16;
    half8 qf0 = *(const half8*)(Qb + (size_t)qrow * DD + 0 * 32 + quad * 8);
    half8 qf1 = *(const half8*)(Qb + (size_t)qrow * DD + 1 * 32 + quad * 8);

    floatx4 o[4];
    for (int nt = 0; nt < 4; nt++) o[nt] = (floatx4){0.f, 0.f, 0.f, 0.f};
    float m_i = 0.0f, l_i = 0.f;   // m_i=0 init (exp-first)

    int srow = lane >> 3;                 // 0..7
    int schunk = (lane & 7) ^ srow;       // swizzled 16B chunk
    const _Float16* kg = Kb + (size_t)(wave * 16 + srow) * DD + schunk * 8;
    const _Float16* vg = VTb + (size_t)(wave * 16 + srow) * 1024 + schunk * 8;
    _Float16* kl0 = &Kt[0][(wave * 16) * 64];
    _Float16* vl0 = &Vt[0][(wave * 16) * 64];
    _Float16* kl1 = &Kt[1][(wave * 16) * 64];
    _Float16* vl1 = &Vt[1][(wave * 16) * 64];

    stage_kv(kg, vg, kl0, vl0, 0);

    for (int kt = 0; kt < 16; kt++) {
        int cur = kt & 1;
        __syncthreads();
        if (kt + 1 < 16)
            stage_kv(kg, vg, cur ? kl0 : kl1, cur ? vl0 : vl1, kt + 1);

        // ---- QK^T (log2 domain) ----
        floatx4 s[4];
        for (int nt = 0; nt < 4; nt++) s[nt] = (floatx4){0.f, 0.f, 0.f, 0.f};
        __builtin_amdgcn_s_setprio(1);
        for (int ks = 0; ks < 2; ks++) {
            half8 qf = ks ? qf1 : qf0;
            for (int nt = 0; nt < 4; nt++) {
                half8 kf = *(const half8*)&Kt[cur][(nt * 16 + l16) * 64
                                                   + (((ks * 4 + quad) ^ l16sw) * 8)];
                s[nt] = __builtin_amdgcn_mfma_f32_16x16x32_f16(kf, qf, s[nt], 0, 0, 0);
            }
        }
        __builtin_amdgcn_s_setprio(0);

        // ---- exp-first softmax: P with STALE m_i; max tree off critical path ----
        float a0 = fmaxf(fmaxf(s[0][0], s[0][1]), fmaxf(s[0][2], s[0][3]));
        float a1 = fmaxf(fmaxf(s[1][0], s[1][1]), fmaxf(s[1][2], s[1][3]));
        float a2 = fmaxf(fmaxf(s[2][0], s[2][1]), fmaxf(s[2][2], s[2][3]));
        float a3 = fmaxf(fmaxf(s[3][0], s[3][1]), fmaxf(s[3][2], s[3][3]));
        float mx = fmaxf(fmaxf(a0, a1), fmaxf(a2, a3));

        for (int nt = 0; nt < 4; nt++)
            for (int r = 0; r < 4; r++)
                s[nt][r] = EXP2F(s[nt][r] - m_i);
        float r0 = (s[0][0] + s[0][1]) + (s[0][2] + s[0][3]);
        float r1 = (s[1][0] + s[1][1]) + (s[1][2] + s[1][3]);
        float r2 = (s[2][0] + s[2][1]) + (s[2][2] + s[2][3]);
        float r3 = (s[3][0] + s[3][1]) + (s[3][2] + s[3][3]);
        float rs = (r0 + r1) + (r2 + r3);

        float mxs = __shfl_xor(mx, 16, 64);
        float rss = __shfl_xor(rs, 16, 64);
        mx = fmaxf(mx, mxs);
        rs += rss;
        mxs = __shfl_xor(mx, 32, 64);
        rss = __shfl_xor(rs, 32, 64);
        mx = fmaxf(mx, mxs);
        rs += rss;

        if (__any(mx > m_i + 11.5443f)) {
            float mnew = fmaxf(m_i, mx);
            float al = EXP2F(m_i - mnew);
            m_i = mnew;
            l_i *= al;
            rs *= al;
            for (int nt = 0; nt < 4; nt++)
                for (int r = 0; r < 4; r++) {
                    s[nt][r] *= al;
                    o[nt][r] *= al;
                }
        }
        l_i += rs;

        // ---- pack P^T tile to per-wave LDS (swizzled) ----
        for (int ntl = 0; ntl < 4; ntl++) {
            half4v p4;
            for (int r = 0; r < 4; r++) p4[r] = (_Float16)s[ntl][r];
            *(half4v*)&PT[wave][l16 * 64 + (((ntl * 2 + (quad >> 1)) ^ l16sw) * 8)
                               + (quad & 1) * 4] = p4;
        }

        // ---- PV ----
        __builtin_amdgcn_s_setprio(1);
        for (int ks2 = 0; ks2 < 2; ks2++) {
            half8 pf = *(const half8*)&PT[wave][l16 * 64 + (((ks2 * 4 + quad) ^ l16sw) * 8)];
            for (int nt = 0; nt < 4; nt++) {
                half8 vf = *(const half8*)&Vt[cur][(nt * 16 + l16) * 64
                                                   + (((ks2 * 4 + quad) ^ l16sw) * 8)];
                o[nt] = __builtin_amdgcn_mfma_f32_16x16x32_f16(vf, pf, o[nt], 0, 0, 0);
            }
        }
        __builtin_amdgcn_s_setprio(0);
    }

    float inv = 1.0f / l_i;
    float* outb = out + ((size_t)b * NN) * DD + h * DHH;
    int row = qt * 64 + wave * 16 + l16;
    for (int nt = 0; nt < 4; nt++) {
        float4 st;
        st.x = o[nt][0] * inv; st.y = o[nt][1] * inv;
        st.z = o[nt][2] * inv; st.w = o[nt][3] * inv;
        *(float4*)&outb[(size_t)row * DD + nt * 16 + quad * 4] = st;
    }
}

extern "C" void kernel_launch(void* const* d_in, const int* in_sizes, int n_in,
                              void* d_out, int out_size, void* d_ws, size_t ws_size,
                              hipStream_t stream) {
    const float* x  = (const float*)d_in[0];
    const float* Wq = (const float*)d_in[1];
    const float* bq = (const float*)d_in[2];
    const float* Wk = (const float*)d_in[3];
    const float* bk = (const float*)d_in[4];
    const float* Wv = (const float*)d_in[5];
    const float* bv = (const float*)d_in[6];
    float* out = (float*)d_out;

    _Float16* Wt  = (_Float16*)d_ws;
    _Float16* QKV = Wt + (size_t)3 * DD * DD;

    hipLaunchKernelGGL(cvt_kernel, dim3(192), dim3(256), 0, stream,
                       Wq, Wk, Wv, Wt);
    hipLaunchKernelGGL(qkv_gemm_kernel, dim3(64, 4, 3), dim3(256), 0, stream,
                       x, Wt, bq, bk, bv, QKV);
    hipLaunchKernelGGL(attn_kernel, dim3(1024), dim3(256), 0, stream, QKV, out);
}